// Round 1
// baseline (191.880 us; speedup 1.0000x reference)
//
#include <hip/hip_runtime.h>

// RelationTransform: out[i] = W[relation[i]] @ node_emb[i]
// N=32768 tokens, EMB=512, 16 relations, fp32 in/out.
// Strategy: counting-sort tokens by relation (ws), then grouped bf16-MFMA GEMM.

#define EMB 512
#define N_RELC 16
#define BM 128
#define BN 128
#define BK 32
#define LDSP 40   // padded LDS row stride in bf16 elems (32 + 8)

typedef __attribute__((ext_vector_type(8))) short bf16x8;
typedef __attribute__((ext_vector_type(4))) float f32x4;

__device__ __forceinline__ unsigned short f2bf(float f) {
  unsigned int u = __float_as_uint(f);
  u += 0x7FFFu + ((u >> 16) & 1u);   // round-to-nearest-even
  return (unsigned short)(u >> 16);
}

__global__ void init_counts(int* cnt) {
  if (threadIdx.x < 32) cnt[threadIdx.x] = 0;
}

__global__ void count_pos(const int* __restrict__ rel, int* cnt, int* pos, int n) {
  int i = blockIdx.x * blockDim.x + threadIdx.x;
  if (i < n) pos[i] = atomicAdd(&cnt[rel[i]], 1);
}

__global__ void prefix_scan(const int* __restrict__ cnt, int* segs) {
  if (threadIdx.x == 0) {
    int acc = 0;
    for (int r = 0; r < N_RELC; ++r) { segs[r] = acc; acc += cnt[r]; }
    segs[N_RELC] = acc;
  }
}

__global__ void scatter_perm(const int* __restrict__ rel, const int* __restrict__ pos,
                             const int* __restrict__ segs, int* perm, int n) {
  int i = blockIdx.x * blockDim.x + threadIdx.x;
  if (i < n) perm[segs[rel[i]] + pos[i]] = i;
}

// Safety-net naive kernel (only if ws too small).
__global__ void naive_kernel(const float* __restrict__ X, const int* __restrict__ rel,
                             const float* __restrict__ W, float* __restrict__ out, int n) {
  int i = blockIdx.x;
  if (i >= n) return;
  int r = rel[i];
  const float* x = X + (size_t)i * EMB;
  const float* Wr = W + (size_t)r * EMB * EMB;
  for (int j = threadIdx.x; j < EMB; j += blockDim.x) {
    const float* w = Wr + (size_t)j * EMB;
    float s = 0.f;
    for (int k = 0; k < EMB; ++k) s += w[k] * x[k];
    out[(size_t)i * EMB + j] = s;
  }
}

__global__ __launch_bounds__(256) void grouped_gemm(
    const float* __restrict__ X, const float* __restrict__ W,
    const int* __restrict__ segs, const int* __restrict__ perm,
    float* __restrict__ out)
{
  __shared__ unsigned short As[BM * LDSP];
  __shared__ unsigned short Bs[BN * LDSP];

  const int r = blockIdx.z;
  const int ct = blockIdx.x;               // column tile: 0..EMB/BN-1
  const int seg0 = segs[r];
  const int count = segs[r + 1] - seg0;
  const int nmt = (count + BM - 1) / BM;
  const float* Wr = W + (size_t)r * EMB * EMB;

  const int tid = threadIdx.x;
  const int lane = tid & 63;
  const int wid = tid >> 6;
  const int wr = wid >> 1;                 // wave row (0..1) -> 64 rows
  const int wc = wid & 1;                  // wave col (0..1) -> 64 cols

  const int srow = tid >> 1;               // staging row 0..127 (2 threads/row)
  const int kblk = (tid & 1) * 16;         // k sub-block 0 or 16

  const int lrow = lane & 15;
  const int lk = (lane >> 4) * 8;          // frag k offset per 16-lane group
  const int lrow4 = (lane >> 4) * 4;       // C/D row base per 16-lane group

  const f32x4 vzero = {0.f, 0.f, 0.f, 0.f};

  for (int mt = blockIdx.y; mt < nmt; mt += gridDim.y) {
    const int row0 = mt * BM;
    int tokA = -1;
    if (row0 + srow < count) tokA = perm[seg0 + row0 + srow];
    const float* bbase = Wr + (size_t)(ct * BN + srow) * EMB;

    f32x4 acc[4][4];
    #pragma unroll
    for (int m = 0; m < 4; ++m)
      #pragma unroll
      for (int n = 0; n < 4; ++n)
        acc[m][n] = vzero;

    for (int kt = 0; kt < EMB / BK; ++kt) {
      const int k0 = kt * BK;
      unsigned short av[16], bv[16];
      if (tokA >= 0) {
        const float* src = X + (size_t)tokA * EMB + k0 + kblk;
        #pragma unroll
        for (int v = 0; v < 4; ++v) {
          f32x4 f = *reinterpret_cast<const f32x4*>(src + v * 4);
          av[v*4+0] = f2bf(f[0]); av[v*4+1] = f2bf(f[1]);
          av[v*4+2] = f2bf(f[2]); av[v*4+3] = f2bf(f[3]);
        }
      } else {
        #pragma unroll
        for (int v = 0; v < 16; ++v) av[v] = 0;
      }
      {
        const float* src = bbase + k0 + kblk;
        #pragma unroll
        for (int v = 0; v < 4; ++v) {
          f32x4 f = *reinterpret_cast<const f32x4*>(src + v * 4);
          bv[v*4+0] = f2bf(f[0]); bv[v*4+1] = f2bf(f[1]);
          bv[v*4+2] = f2bf(f[2]); bv[v*4+3] = f2bf(f[3]);
        }
      }
      __syncthreads();   // previous iteration's readers done
      *reinterpret_cast<bf16x8*>(&As[srow * LDSP + kblk])     = *reinterpret_cast<const bf16x8*>(&av[0]);
      *reinterpret_cast<bf16x8*>(&As[srow * LDSP + kblk + 8]) = *reinterpret_cast<const bf16x8*>(&av[8]);
      *reinterpret_cast<bf16x8*>(&Bs[srow * LDSP + kblk])     = *reinterpret_cast<const bf16x8*>(&bv[0]);
      *reinterpret_cast<bf16x8*>(&Bs[srow * LDSP + kblk + 8]) = *reinterpret_cast<const bf16x8*>(&bv[8]);
      __syncthreads();   // writes visible

      bf16x8 af[4], bf[4];
      #pragma unroll
      for (int m = 0; m < 4; ++m)
        af[m] = *reinterpret_cast<const bf16x8*>(&As[(wr * 64 + m * 16 + lrow) * LDSP + lk]);
      #pragma unroll
      for (int n = 0; n < 4; ++n)
        bf[n] = *reinterpret_cast<const bf16x8*>(&Bs[(wc * 64 + n * 16 + lrow) * LDSP + lk]);
      #pragma unroll
      for (int m = 0; m < 4; ++m)
        #pragma unroll
        for (int n = 0; n < 4; ++n)
          acc[m][n] = __builtin_amdgcn_mfma_f32_16x16x32_bf16(af[m], bf[n], acc[m][n], 0, 0, 0);
    }

    // Epilogue: D mapping col=lane&15, row=(lane>>4)*4+reg  [m89-verified]
    #pragma unroll
    for (int m = 0; m < 4; ++m) {
      const int gmb = row0 + wr * 64 + m * 16 + lrow4;
      #pragma unroll
      for (int rg = 0; rg < 4; ++rg) {
        const int gm = gmb + rg;
        if (gm < count) {
          const int tok = perm[seg0 + gm];
          float* orow = out + (size_t)tok * EMB + ct * BN + wc * 64;
          #pragma unroll
          for (int n = 0; n < 4; ++n)
            orow[n * 16 + lrow] = acc[m][n][rg];
        }
      }
    }
    __syncthreads();   // protect LDS before next mt iteration's writes
  }
}

extern "C" void kernel_launch(void* const* d_in, const int* in_sizes, int n_in,
                              void* d_out, int out_size, void* d_ws, size_t ws_size,
                              hipStream_t stream) {
  const float* X  = (const float*)d_in[0];
  const int* rel  = (const int*)d_in[1];
  const float* W  = (const float*)d_in[2];
  float* out      = (float*)d_out;
  const int n = in_sizes[1];

  const size_t need = (size_t)(64 + 2 * n) * sizeof(int);
  if (ws_size < need) {
    naive_kernel<<<n, 256, 0, stream>>>(X, rel, W, out, n);
    return;
  }

  int* cnt  = (int*)d_ws;        // [0,16): counts (zeroed each call)
  int* segs = cnt + 16;          // [16,33): segment starts (17)
  int* pos  = cnt + 64;          // [64, 64+n): rank within relation
  int* perm = pos + n;           // [64+n, 64+2n): sorted token ids

  init_counts<<<1, 32, 0, stream>>>(cnt);
  count_pos<<<(n + 255) / 256, 256, 0, stream>>>(rel, cnt, pos, n);
  prefix_scan<<<1, 1, 0, stream>>>(cnt, segs);
  scatter_perm<<<(n + 255) / 256, 256, 0, stream>>>(rel, pos, segs, perm, n);

  dim3 grid(EMB / BN, 8, N_RELC);
  grouped_gemm<<<grid, 256, 0, stream>>>(X, W, segs, perm, out);
}

// Round 2
// 97.137 us; speedup vs baseline: 1.9754x; 1.9754x over previous
//
#include <hip/hip_runtime.h>
#include <stdint.h>

// RelationTransform: out[i] = W[relation[i]] @ node_emb[i]
// N=32768 tokens, EMB=512, 16 relations, fp32 in/out.
// Plan: LDS-histogram sort -> gather+convert X to bf16 (relation-sorted,
// BM-padded) -> convert W to bf16 -> grouped MFMA GEMM with global_load_lds.

#define EMB 512
#define N_RELC 16
#define BM 128
#define BN 128
#define BK 32
#define LDSP 40   // padded stride for fallback kernel

typedef __attribute__((ext_vector_type(8))) short bf16x8;
typedef __attribute__((ext_vector_type(4))) float f32x4;

__device__ __forceinline__ unsigned short f2bf(float f) {
  unsigned int u = __float_as_uint(f);
  u += 0x7FFFu + ((u >> 16) & 1u);   // round-to-nearest-even
  return (unsigned short)(u >> 16);
}

__device__ __forceinline__ void gload_lds16(const void* g, void* l) {
  auto gp = (const __attribute__((address_space(1))) unsigned int*)(uintptr_t)g;
  auto lp = (__attribute__((address_space(3))) unsigned int*)(uintptr_t)l;
  __builtin_amdgcn_global_load_lds(gp, lp, 16, 0, 0);
}

__global__ void init_counts(int* cnt) {
  if (threadIdx.x < 32) cnt[threadIdx.x] = 0;
}

// Per-block LDS histogram -> one global atomic per (block, relation).
__global__ __launch_bounds__(256) void histo_rank(const int* __restrict__ rel,
                                                  int* cnt, int* pos, int n) {
  __shared__ int lcnt[N_RELC];
  __shared__ int lbase[N_RELC];
  const int tid = threadIdx.x;
  if (tid < N_RELC) lcnt[tid] = 0;
  __syncthreads();
  const int i = blockIdx.x * blockDim.x + tid;
  int r = 0, myrank = 0;
  if (i < n) { r = rel[i]; myrank = atomicAdd(&lcnt[r], 1); }
  __syncthreads();
  if (tid < N_RELC) lbase[tid] = atomicAdd(&cnt[tid], lcnt[tid]);
  __syncthreads();
  if (i < n) pos[i] = lbase[r] + myrank;
}

// Padded (to BM) segment bases + tile table.
__global__ void prefix_tiles(const int* __restrict__ cnt, int* pbase,
                             int* tinfo, int maxt) {
  if (threadIdx.x != 0) return;
  int acc = 0, t = 0;
  for (int r = 0; r < N_RELC; ++r) {
    pbase[r] = acc;
    const int nt = (cnt[r] + BM - 1) / BM;
    for (int m = 0; m < nt; ++m) tinfo[t++] = (r << 16) | m;
    acc += nt * BM;
  }
  pbase[N_RELC] = acc;
  for (int x = t; x < maxt; ++x) tinfo[x] = -1;
}

// Gather X rows into sorted+padded bf16 Xs; record token id per padded row.
__global__ __launch_bounds__(256) void gather_convert(
    const float* __restrict__ X, const int* __restrict__ rel,
    const int* __restrict__ pos, const int* __restrict__ pbase,
    unsigned short* __restrict__ Xs, int* __restrict__ ptok, int n)
{
  const int row = blockIdx.x * 4 + (threadIdx.x >> 6);
  const int lane = threadIdx.x & 63;
  if (row >= n) return;
  const int dst = pbase[rel[row]] + pos[row];
  if (lane == 0) ptok[dst] = row;
  const float* src = X + (size_t)row * EMB + lane * 8;
  f32x4 a = *reinterpret_cast<const f32x4*>(src);
  f32x4 b = *reinterpret_cast<const f32x4*>(src + 4);
  bf16x8 o;
  o[0] = f2bf(a[0]); o[1] = f2bf(a[1]); o[2] = f2bf(a[2]); o[3] = f2bf(a[3]);
  o[4] = f2bf(b[0]); o[5] = f2bf(b[1]); o[6] = f2bf(b[2]); o[7] = f2bf(b[3]);
  *reinterpret_cast<bf16x8*>(Xs + (size_t)dst * EMB + lane * 8) = o;
}

// Zero pad rows of Xs; ptok = -1 for pads.
__global__ __launch_bounds__(256) void zero_pads(const int* __restrict__ cnt,
                                                 const int* __restrict__ pbase,
                                                 unsigned short* __restrict__ Xs,
                                                 int* __restrict__ ptok) {
  const int r = blockIdx.x;
  const int start = pbase[r] + cnt[r];
  const int end = pbase[r + 1];
  const int nvec = (end - start) * (EMB / 8);
  unsigned short* p = Xs + (size_t)start * EMB;
  const bf16x8 z = {0, 0, 0, 0, 0, 0, 0, 0};
  for (int v = threadIdx.x; v < nvec; v += blockDim.x)
    *reinterpret_cast<bf16x8*>(p + (size_t)v * 8) = z;
  for (int j = start + threadIdx.x; j < end; j += blockDim.x) ptok[j] = -1;
}

__global__ __launch_bounds__(256) void convert_W(const float* __restrict__ W,
                                                 unsigned short* __restrict__ Ws,
                                                 int welems) {
  const size_t i = ((size_t)blockIdx.x * 256 + threadIdx.x) * 8;
  if (i >= (size_t)welems) return;
  f32x4 a = *reinterpret_cast<const f32x4*>(W + i);
  f32x4 b = *reinterpret_cast<const f32x4*>(W + i + 4);
  bf16x8 o;
  o[0] = f2bf(a[0]); o[1] = f2bf(a[1]); o[2] = f2bf(a[2]); o[3] = f2bf(a[3]);
  o[4] = f2bf(b[0]); o[5] = f2bf(b[1]); o[6] = f2bf(b[2]); o[7] = f2bf(b[3]);
  *reinterpret_cast<bf16x8*>(Ws + i) = o;
}

// m97-structure grouped GEMM: 128x128 tile, BK=32, global_load_lds staging.
__global__ __launch_bounds__(256) void grouped_gemm2(
    const unsigned short* __restrict__ Xs, const unsigned short* __restrict__ Ws,
    const int* __restrict__ pbase, const int* __restrict__ tinfo,
    const int* __restrict__ ptok, float* __restrict__ out)
{
  __shared__ unsigned short As[BM * BK];   // linear: row stride 32 bf16 (64 B)
  __shared__ unsigned short Bs[BN * BK];

  const int info = tinfo[blockIdx.y];
  if (info < 0) return;
  const int r = info >> 16;
  const int mt = info & 0xFFFF;
  const int ct = blockIdx.x;
  const int prow0 = pbase[r] + mt * BM;

  const unsigned short* Ab = Xs + (size_t)prow0 * EMB;
  const unsigned short* Bb = Ws + ((size_t)r * EMB + (size_t)ct * BN) * EMB;

  const int tid = threadIdx.x;
  const int lane = tid & 63;
  const int wid = tid >> 6;
  const int wr = wid >> 1, wc = wid & 1;
  const int lrow = lane & 15;
  const int lk = (lane >> 4) * 8;
  const int lrow4 = (lane >> 4) * 4;

  // staging: chunk c = wid*2+t covers bytes [c*1024, c*1024+1024) of the 8KB tile
  const int c0 = wid * 2;
  const int srowA0 = c0 * 16 + (lane >> 2);        // row for chunk c0
  const int srowA1 = (c0 + 1) * 16 + (lane >> 2);  // row for chunk c0+1
  const int scol = (lane & 3) * 8;                 // k elem offset within BK

  f32x4 acc[4][4];
  const f32x4 vzero = {0.f, 0.f, 0.f, 0.f};
  #pragma unroll
  for (int m = 0; m < 4; ++m)
    #pragma unroll
    for (int nn = 0; nn < 4; ++nn) acc[m][nn] = vzero;

  for (int kt = 0; kt < EMB / BK; ++kt) {
    const int k0 = kt * BK;
    gload_lds16(Ab + (size_t)srowA0 * EMB + k0 + scol, (char*)As + c0 * 1024);
    gload_lds16(Ab + (size_t)srowA1 * EMB + k0 + scol, (char*)As + (c0 + 1) * 1024);
    gload_lds16(Bb + (size_t)srowA0 * EMB + k0 + scol, (char*)Bs + c0 * 1024);
    gload_lds16(Bb + (size_t)srowA1 * EMB + k0 + scol, (char*)Bs + (c0 + 1) * 1024);
    __syncthreads();   // drains vmcnt: staged data visible

    bf16x8 af[4], bfr[4];
    #pragma unroll
    for (int m = 0; m < 4; ++m)
      af[m] = *reinterpret_cast<const bf16x8*>(&As[(wr * 64 + m * 16 + lrow) * BK + lk]);
    #pragma unroll
    for (int nn = 0; nn < 4; ++nn)
      bfr[nn] = *reinterpret_cast<const bf16x8*>(&Bs[(wc * 64 + nn * 16 + lrow) * BK + lk]);
    #pragma unroll
    for (int m = 0; m < 4; ++m)
      #pragma unroll
      for (int nn = 0; nn < 4; ++nn)
        acc[m][nn] = __builtin_amdgcn_mfma_f32_16x16x32_bf16(af[m], bfr[nn], acc[m][nn], 0, 0, 0);
    __syncthreads();   // readers done before next stage overwrites
  }

  // Epilogue: D mapping col=lane&15, row=(lane>>4)*4+reg
  #pragma unroll
  for (int m = 0; m < 4; ++m) {
    const int base = prow0 + wr * 64 + m * 16 + lrow4;
    #pragma unroll
    for (int rg = 0; rg < 4; ++rg) {
      const int tok = ptok[base + rg];
      if (tok >= 0) {
        float* orow = out + (size_t)tok * EMB + ct * BN + wc * 64;
        #pragma unroll
        for (int nn = 0; nn < 4; ++nn)
          orow[nn * 16 + lrow] = acc[m][nn][rg];
      }
    }
  }
}

// ---------------- fallback paths (proven round-1 code) ----------------

__global__ void count_pos(const int* __restrict__ rel, int* cnt, int* pos, int n) {
  int i = blockIdx.x * blockDim.x + threadIdx.x;
  if (i < n) pos[i] = atomicAdd(&cnt[rel[i]], 1);
}

__global__ void prefix_scan(const int* __restrict__ cnt, int* segs) {
  if (threadIdx.x == 0) {
    int acc = 0;
    for (int r = 0; r < N_RELC; ++r) { segs[r] = acc; acc += cnt[r]; }
    segs[N_RELC] = acc;
  }
}

__global__ void scatter_perm(const int* __restrict__ rel, const int* __restrict__ pos,
                             const int* __restrict__ segs, int* perm, int n) {
  int i = blockIdx.x * blockDim.x + threadIdx.x;
  if (i < n) perm[segs[rel[i]] + pos[i]] = i;
}

__global__ void naive_kernel(const float* __restrict__ X, const int* __restrict__ rel,
                             const float* __restrict__ W, float* __restrict__ out, int n) {
  int i = blockIdx.x;
  if (i >= n) return;
  int r = rel[i];
  const float* x = X + (size_t)i * EMB;
  const float* Wr = W + (size_t)r * EMB * EMB;
  for (int j = threadIdx.x; j < EMB; j += blockDim.x) {
    const float* w = Wr + (size_t)j * EMB;
    float s = 0.f;
    for (int k = 0; k < EMB; ++k) s += w[k] * x[k];
    out[(size_t)i * EMB + j] = s;
  }
}

__global__ __launch_bounds__(256) void grouped_gemm(
    const float* __restrict__ X, const float* __restrict__ W,
    const int* __restrict__ segs, const int* __restrict__ perm,
    float* __restrict__ out)
{
  __shared__ unsigned short As[BM * LDSP];
  __shared__ unsigned short Bs[BN * LDSP];
  const int r = blockIdx.z;
  const int ct = blockIdx.x;
  const int seg0 = segs[r];
  const int count = segs[r + 1] - seg0;
  const int nmt = (count + BM - 1) / BM;
  const float* Wr = W + (size_t)r * EMB * EMB;
  const int tid = threadIdx.x;
  const int lane = tid & 63;
  const int wid = tid >> 6;
  const int wr = wid >> 1, wc = wid & 1;
  const int srow = tid >> 1;
  const int kblk = (tid & 1) * 16;
  const int lrow = lane & 15;
  const int lk = (lane >> 4) * 8;
  const int lrow4 = (lane >> 4) * 4;
  const f32x4 vzero = {0.f, 0.f, 0.f, 0.f};

  for (int mt = blockIdx.y; mt < nmt; mt += gridDim.y) {
    const int row0 = mt * BM;
    int tokA = -1;
    if (row0 + srow < count) tokA = perm[seg0 + row0 + srow];
    const float* bbase = Wr + (size_t)(ct * BN + srow) * EMB;
    f32x4 acc[4][4];
    #pragma unroll
    for (int m = 0; m < 4; ++m)
      #pragma unroll
      for (int nn = 0; nn < 4; ++nn) acc[m][nn] = vzero;

    for (int kt = 0; kt < EMB / BK; ++kt) {
      const int k0 = kt * BK;
      unsigned short av[16], bv[16];
      if (tokA >= 0) {
        const float* src = X + (size_t)tokA * EMB + k0 + kblk;
        #pragma unroll
        for (int v = 0; v < 4; ++v) {
          f32x4 f = *reinterpret_cast<const f32x4*>(src + v * 4);
          av[v*4+0] = f2bf(f[0]); av[v*4+1] = f2bf(f[1]);
          av[v*4+2] = f2bf(f[2]); av[v*4+3] = f2bf(f[3]);
        }
      } else {
        #pragma unroll
        for (int v = 0; v < 16; ++v) av[v] = 0;
      }
      {
        const float* src = bbase + k0 + kblk;
        #pragma unroll
        for (int v = 0; v < 4; ++v) {
          f32x4 f = *reinterpret_cast<const f32x4*>(src + v * 4);
          bv[v*4+0] = f2bf(f[0]); bv[v*4+1] = f2bf(f[1]);
          bv[v*4+2] = f2bf(f[2]); bv[v*4+3] = f2bf(f[3]);
        }
      }
      __syncthreads();
      *reinterpret_cast<bf16x8*>(&As[srow * LDSP + kblk])     = *reinterpret_cast<const bf16x8*>(&av[0]);
      *reinterpret_cast<bf16x8*>(&As[srow * LDSP + kblk + 8]) = *reinterpret_cast<const bf16x8*>(&av[8]);
      *reinterpret_cast<bf16x8*>(&Bs[srow * LDSP + kblk])     = *reinterpret_cast<const bf16x8*>(&bv[0]);
      *reinterpret_cast<bf16x8*>(&Bs[srow * LDSP + kblk + 8]) = *reinterpret_cast<const bf16x8*>(&bv[8]);
      __syncthreads();

      bf16x8 af[4], bfr[4];
      #pragma unroll
      for (int m = 0; m < 4; ++m)
        af[m] = *reinterpret_cast<const bf16x8*>(&As[(wr * 64 + m * 16 + lrow) * LDSP + lk]);
      #pragma unroll
      for (int nn = 0; nn < 4; ++nn)
        bfr[nn] = *reinterpret_cast<const bf16x8*>(&Bs[(wc * 64 + nn * 16 + lrow) * LDSP + lk]);
      #pragma unroll
      for (int m = 0; m < 4; ++m)
        #pragma unroll
        for (int nn = 0; nn < 4; ++nn)
          acc[m][nn] = __builtin_amdgcn_mfma_f32_16x16x32_bf16(af[m], bfr[nn], acc[m][nn], 0, 0, 0);
    }
    #pragma unroll
    for (int m = 0; m < 4; ++m) {
      const int gmb = row0 + wr * 64 + m * 16 + lrow4;
      #pragma unroll
      for (int rg = 0; rg < 4; ++rg) {
        const int gm = gmb + rg;
        if (gm < count) {
          const int tok = perm[seg0 + gm];
          float* orow = out + (size_t)tok * EMB + ct * BN + wc * 64;
          #pragma unroll
          for (int nn = 0; nn < 4; ++nn)
            orow[nn * 16 + lrow] = acc[m][nn][rg];
        }
      }
    }
    __syncthreads();
  }
}

extern "C" void kernel_launch(void* const* d_in, const int* in_sizes, int n_in,
                              void* d_out, int out_size, void* d_ws, size_t ws_size,
                              hipStream_t stream) {
  const float* X  = (const float*)d_in[0];
  const int* rel  = (const int*)d_in[1];
  const float* W  = (const float*)d_in[2];
  float* out      = (float*)d_out;
  const int n = in_sizes[1];
  const int welems = in_sizes[2];               // n_rel * EMB * EMB
  const int padn = n + N_RELC * BM;
  const int maxt = (n + BM - 1) / BM + N_RELC;

  // full-path ws layout
  const size_t ints = (size_t)64 + n + padn + maxt + 64;
  const size_t off0 = ((ints * sizeof(int) + 255) / 256) * 256;      // Ws
  const size_t off1 = off0 + (((size_t)welems * 2 + 255) / 256) * 256; // Xs
  const size_t need_full = off1 + (size_t)padn * EMB * 2;

  if (ws_size >= need_full) {
    int* cnt   = (int*)d_ws;       // 16
    int* pbase = cnt + 16;         // 17
    int* pos   = cnt + 64;         // n
    int* ptok  = pos + n;          // padn
    int* tinfo = ptok + padn;      // maxt
    unsigned short* Ws = (unsigned short*)((char*)d_ws + off0);
    unsigned short* Xs = (unsigned short*)((char*)d_ws + off1);

    init_counts<<<1, 32, 0, stream>>>(cnt);
    histo_rank<<<(n + 255) / 256, 256, 0, stream>>>(rel, cnt, pos, n);
    prefix_tiles<<<1, 1, 0, stream>>>(cnt, pbase, tinfo, maxt);
    gather_convert<<<(n + 3) / 4, 256, 0, stream>>>(X, rel, pos, pbase, Xs, ptok, n);
    zero_pads<<<N_RELC, 256, 0, stream>>>(cnt, pbase, Xs, ptok);
    convert_W<<<(welems / 8 + 255) / 256, 256, 0, stream>>>(W, Ws, welems);

    dim3 grid(EMB / BN, maxt);
    grouped_gemm2<<<grid, 256, 0, stream>>>(Xs, Ws, pbase, tinfo, ptok, out);
    return;
  }

  const size_t need_mid = (size_t)(64 + 2 * n) * sizeof(int);
  if (ws_size >= need_mid) {
    int* cnt  = (int*)d_ws;
    int* segs = cnt + 16;
    int* pos  = cnt + 64;
    int* perm = pos + n;
    init_counts<<<1, 32, 0, stream>>>(cnt);
    count_pos<<<(n + 255) / 256, 256, 0, stream>>>(rel, cnt, pos, n);
    prefix_scan<<<1, 1, 0, stream>>>(cnt, segs);
    scatter_perm<<<(n + 255) / 256, 256, 0, stream>>>(rel, pos, segs, perm, n);
    dim3 grid(EMB / BN, 8, N_RELC);
    grouped_gemm<<<grid, 256, 0, stream>>>(X, W, segs, perm, out);
    return;
  }

  naive_kernel<<<n, 256, 0, stream>>>(X, rel, W, out, n);
}

// Round 3
// 84.342 us; speedup vs baseline: 2.2750x; 1.1517x over previous
//
#include <hip/hip_runtime.h>
#include <hip/hip_bf16.h>
#include <stdint.h>

// RelationTransform: out[i] = W[relation[i]] @ node_emb[i]
// N=32768, EMB=512, 16 relations, fp32 in/out.
// Fully fused: histogram-sort -> grouped GEMM that gathers fp32 X rows and
// fp32 W tiles directly to LDS via global_load_lds (per-lane global addrs,
// XOR-swizzled source), converts to bf16 after ds_read, MFMA accumulates.
// 2-phase prefetch: counted vmcnt(8), raw s_barrier, never drain in-loop.

#define EMB 512
#define N_RELC 16
#define BM 128
#define BN 128
#define BK 32
#define NKT (EMB / BK)   // 16

typedef __attribute__((ext_vector_type(4))) float f32x4;
typedef __attribute__((ext_vector_type(8))) short bf16x8;

__device__ __forceinline__ void gload_lds16(const void* g, void* l) {
  __builtin_amdgcn_global_load_lds(
      (const __attribute__((address_space(1))) unsigned int*)(uintptr_t)g,
      (__attribute__((address_space(3))) unsigned int*)(uintptr_t)l, 16, 0, 0);
}

__device__ __forceinline__ bf16x8 cvt8(f32x4 lo, f32x4 hi) {
  bf16x8 o;
  o[0] = (short)__bfloat16_as_ushort(__float2bfloat16(lo[0]));
  o[1] = (short)__bfloat16_as_ushort(__float2bfloat16(lo[1]));
  o[2] = (short)__bfloat16_as_ushort(__float2bfloat16(lo[2]));
  o[3] = (short)__bfloat16_as_ushort(__float2bfloat16(lo[3]));
  o[4] = (short)__bfloat16_as_ushort(__float2bfloat16(hi[0]));
  o[5] = (short)__bfloat16_as_ushort(__float2bfloat16(hi[1]));
  o[6] = (short)__bfloat16_as_ushort(__float2bfloat16(hi[2]));
  o[7] = (short)__bfloat16_as_ushort(__float2bfloat16(hi[3]));
  return o;
}

__global__ void init_counts(int* cnt) {
  if (threadIdx.x < 32) cnt[threadIdx.x] = 0;
}

// Per-block LDS histogram rank; also fills ptok[0..padn) with -1.
__global__ __launch_bounds__(256) void histo_rank_fill(
    const int* __restrict__ rel, int* cnt, int* pos, int* ptok,
    int n, int padn) {
  __shared__ int lcnt[N_RELC];
  __shared__ int lbase[N_RELC];
  const int tid = threadIdx.x;
  if (tid < N_RELC) lcnt[tid] = 0;
  __syncthreads();
  const int i = blockIdx.x * blockDim.x + tid;
  if (i < padn) ptok[i] = -1;
  int r = 0, myrank = 0;
  if (i < n) { r = rel[i]; myrank = atomicAdd(&lcnt[r], 1); }
  __syncthreads();
  if (tid < N_RELC) lbase[tid] = atomicAdd(&cnt[tid], lcnt[tid]);
  __syncthreads();
  if (i < n) pos[i] = lbase[r] + myrank;
}

// Padded segment bases + tile table (1 block, 64 threads).
__global__ void prefix_tiles64(const int* __restrict__ cnt, int* pbase,
                               int* tinfo, int maxt) {
  __shared__ int sb[N_RELC + 1];
  __shared__ int st[N_RELC + 1];
  if (threadIdx.x == 0) {
    int acc = 0, t = 0;
    for (int r = 0; r < N_RELC; ++r) {
      sb[r] = acc; st[r] = t;
      const int nt = (cnt[r] + BM - 1) / BM;
      acc += nt * BM;
      t += nt;
    }
    sb[N_RELC] = acc; st[N_RELC] = t;
  }
  __syncthreads();
  for (int i = threadIdx.x; i <= N_RELC; i += blockDim.x) pbase[i] = sb[i];
  for (int x = threadIdx.x; x < maxt; x += blockDim.x) {
    int v = -1;
    #pragma unroll
    for (int r = 0; r < N_RELC; ++r)
      if (x >= st[r] && x < st[r + 1]) v = (r << 16) | (x - st[r]);
    tinfo[x] = v;
  }
}

__global__ __launch_bounds__(256) void scatter_ptok(
    const int* __restrict__ rel, const int* __restrict__ pos,
    const int* __restrict__ pbase, int* __restrict__ ptok, int n) {
  const int i = blockIdx.x * blockDim.x + threadIdx.x;
  if (i < n) ptok[pbase[rel[i]] + pos[i]] = i;
}

// Fused grouped GEMM. LDS tiles are fp32 [128][32], XOR-swizzled in 16B
// slots: phys_slot = log_slot ^ (row & 7). Write side achieved by inverse-
// swizzling the per-lane GLOBAL source column (global_load_lds dest is
// linear base + lane*16). bf16 conversion after ds_read.
#define COMPUTE_STEP(CURBUF)                                                   \
  {                                                                            \
    bf16x8 af[4], bfr[4];                                                      \
    _Pragma("unroll")                                                          \
    for (int m = 0; m < 4; ++m) {                                              \
      const float* base = &As[CURBUF][(wr * 64 + m * 16 + lrow) * BK];         \
      f32x4 lo = *(const f32x4*)(base + (((gl << 1) ^ sw) << 2));              \
      f32x4 hi = *(const f32x4*)(base + ((((gl << 1) | 1) ^ sw) << 2));        \
      af[m] = cvt8(lo, hi);                                                    \
    }                                                                          \
    _Pragma("unroll")                                                          \
    for (int nn = 0; nn < 4; ++nn) {                                           \
      const float* base = &Bs[CURBUF][(wc * 64 + nn * 16 + lrow) * BK];        \
      f32x4 lo = *(const f32x4*)(base + (((gl << 1) ^ sw) << 2));              \
      f32x4 hi = *(const f32x4*)(base + ((((gl << 1) | 1) ^ sw) << 2));        \
      bfr[nn] = cvt8(lo, hi);                                                  \
    }                                                                          \
    _Pragma("unroll")                                                          \
    for (int m = 0; m < 4; ++m)                                                \
      _Pragma("unroll")                                                        \
      for (int nn = 0; nn < 4; ++nn)                                           \
        acc[m][nn] = __builtin_amdgcn_mfma_f32_16x16x32_bf16(                  \
            af[m], bfr[nn], acc[m][nn], 0, 0, 0);                              \
  }

__global__ __launch_bounds__(256, 2) void grouped_gemm3(
    const float* __restrict__ X, const float* __restrict__ W,
    const int* __restrict__ pbase, const int* __restrict__ tinfo,
    const int* __restrict__ ptok, float* __restrict__ out)
{
  __shared__ float As[2][BM * BK];   // 16 KB each buffer
  __shared__ float Bs[2][BN * BK];

  const int info = tinfo[blockIdx.y];
  if (info < 0) return;
  const int r = info >> 16;
  const int mt = info & 0xFFFF;
  const int ct = blockIdx.x;
  const int prow0 = pbase[r] + mt * BM;

  const int tid = threadIdx.x;
  const int lane = tid & 63;
  const int wid = tid >> 6;
  const int wr = wid >> 1, wc = wid & 1;
  const int lrow = lane & 15;
  const int lrow4 = (lane >> 4) * 4;
  const int gl = lane >> 4;        // logical 16B-pair (granule) 0..3
  const int sw = lane & 7;         // read swizzle pattern (= row & 7)

  // staging: chunk c = q*4 + wid (1KB each); lane covers rows c*8 + (lane>>3),
  // phys slot lane&7. Inverse-swizzled global column:
  const int colsw = (((lane & 7) ^ (lane >> 3)) << 2);   // fp32 units
  const float* Wr = W + (size_t)r * EMB * EMB;

  const float* asrc[4];
  const float* bsrc[4];
  #pragma unroll
  for (int q = 0; q < 4; ++q) {
    const int row = q * 32 + wid * 8 + (lane >> 3);
    int t = ptok[prow0 + row];
    if (t < 0) t = 0;                       // pad rows read token 0 (discarded)
    asrc[q] = X + (size_t)t * EMB + colsw;
    bsrc[q] = Wr + (size_t)(ct * BN + row) * EMB + colsw;
  }

  f32x4 acc[4][4];
  const f32x4 vzero = {0.f, 0.f, 0.f, 0.f};
  #pragma unroll
  for (int m = 0; m < 4; ++m)
    #pragma unroll
    for (int nn = 0; nn < 4; ++nn) acc[m][nn] = vzero;

#define STAGE(BUF, KT)                                                         \
  {                                                                            \
    const int k0_ = (KT) * BK;                                                 \
    _Pragma("unroll")                                                          \
    for (int q = 0; q < 4; ++q) {                                              \
      gload_lds16(asrc[q] + k0_, (char*)&As[BUF][0] + (q * 4 + wid) * 1024);   \
      gload_lds16(bsrc[q] + k0_, (char*)&Bs[BUF][0] + (q * 4 + wid) * 1024);   \
    }                                                                          \
  }

  STAGE(0, 0);
  int cur = 0;
  for (int kt = 0; kt < NKT - 1; ++kt) {
    STAGE(cur ^ 1, kt + 1);                       // 8 loads in flight for next
    asm volatile("s_waitcnt vmcnt(8)" ::: "memory");  // current tile landed
    __builtin_amdgcn_s_barrier();
    asm volatile("" ::: "memory");                // pin ds_reads below barrier
    COMPUTE_STEP(cur);
    asm volatile("s_waitcnt lgkmcnt(0)" ::: "memory");
    __builtin_amdgcn_s_barrier();                 // readers done before overwrite
    cur ^= 1;
  }
  asm volatile("s_waitcnt vmcnt(0)" ::: "memory");
  __builtin_amdgcn_s_barrier();
  asm volatile("" ::: "memory");
  COMPUTE_STEP(cur);

  // Epilogue: D mapping col=lane&15, row=(lane>>4)*4+reg
  #pragma unroll
  for (int m = 0; m < 4; ++m) {
    const int base = prow0 + wr * 64 + m * 16 + lrow4;
    #pragma unroll
    for (int rg = 0; rg < 4; ++rg) {
      const int tok = ptok[base + rg];
      if (tok >= 0) {
        float* orow = out + (size_t)tok * EMB + ct * BN + wc * 64;
        #pragma unroll
        for (int nn = 0; nn < 4; ++nn)
          orow[nn * 16 + lrow] = acc[m][nn][rg];
      }
    }
  }
}

// Safety-net naive kernel (only if ws too small).
__global__ void naive_kernel(const float* __restrict__ X, const int* __restrict__ rel,
                             const float* __restrict__ W, float* __restrict__ out, int n) {
  int i = blockIdx.x;
  if (i >= n) return;
  int r = rel[i];
  const float* x = X + (size_t)i * EMB;
  const float* Wr = W + (size_t)r * EMB * EMB;
  for (int j = threadIdx.x; j < EMB; j += blockDim.x) {
    const float* w = Wr + (size_t)j * EMB;
    float s = 0.f;
    for (int k = 0; k < EMB; ++k) s += w[k] * x[k];
    out[(size_t)i * EMB + j] = s;
  }
}

extern "C" void kernel_launch(void* const* d_in, const int* in_sizes, int n_in,
                              void* d_out, int out_size, void* d_ws, size_t ws_size,
                              hipStream_t stream) {
  const float* X  = (const float*)d_in[0];
  const int* rel  = (const int*)d_in[1];
  const float* W  = (const float*)d_in[2];
  float* out      = (float*)d_out;
  const int n = in_sizes[1];
  const int padn = n + N_RELC * BM;
  const int maxt = (n + BM - 1) / BM + N_RELC;

  const size_t need = (size_t)(64 + n + padn + maxt) * sizeof(int);
  if (ws_size < need) {
    naive_kernel<<<n, 256, 0, stream>>>(X, rel, W, out, n);
    return;
  }

  int* cnt   = (int*)d_ws;       // 16 (+pad)
  int* pbase = cnt + 16;         // 17
  int* pos   = cnt + 64;         // n
  int* ptok  = pos + n;          // padn
  int* tinfo = ptok + padn;      // maxt

  init_counts<<<1, 32, 0, stream>>>(cnt);
  histo_rank_fill<<<(padn + 255) / 256, 256, 0, stream>>>(rel, cnt, pos, ptok, n, padn);
  prefix_tiles64<<<1, 64, 0, stream>>>(cnt, pbase, tinfo, maxt);
  scatter_ptok<<<(n + 255) / 256, 256, 0, stream>>>(rel, pos, pbase, ptok, n);

  dim3 grid(EMB / BN, maxt);
  grouped_gemm3<<<grid, 256, 0, stream>>>(X, W, pbase, tinfo, ptok, out);
}

// Round 4
// 82.816 us; speedup vs baseline: 2.3169x; 1.0184x over previous
//
#include <hip/hip_runtime.h>
#include <stdint.h>

// RelationTransform: out[i] = W[relation[i]] @ node_emb[i]
// N=32768, EMB=512, 16 relations, fp32 in/out.
// Prepass: histogram sort (ptok) + W->bf16 convert (ws).
// GEMM: fused X-gather (fp32->reg->cvt->LDS), bf16 W staging, pad-40 LDS,
// 512-thread blocks, reg-prefetch pipeline with raw barriers (1/iter),
// grid transposed so the 4 column-tiles of an m-tile share an XCD L2.

#define EMB 512
#define N_RELC 16
#define BM 128
#define BN 128
#define BK 32
#define NKT (EMB / BK)   // 16
#define LDP 40           // padded LDS row stride in bf16 (proven 2-way-free)

typedef __attribute__((ext_vector_type(4))) float f32x4;
typedef __attribute__((ext_vector_type(8))) short bf16x8;

__device__ __forceinline__ unsigned short f2bf(float f) {
  unsigned int u = __float_as_uint(f);
  u += 0x7FFFu + ((u >> 16) & 1u);   // round-to-nearest-even
  return (unsigned short)(u >> 16);
}

__global__ void init_counts(int* cnt) {
  if (threadIdx.x < 32) cnt[threadIdx.x] = 0;
}

// Per-block LDS histogram rank; also fills ptok[0..padn) with -1.
__global__ __launch_bounds__(256) void histo_rank_fill(
    const int* __restrict__ rel, int* cnt, int* pos, int* ptok,
    int n, int padn) {
  __shared__ int lcnt[N_RELC];
  __shared__ int lbase[N_RELC];
  const int tid = threadIdx.x;
  if (tid < N_RELC) lcnt[tid] = 0;
  __syncthreads();
  const int i = blockIdx.x * blockDim.x + tid;
  if (i < padn) ptok[i] = -1;
  int r = 0, myrank = 0;
  if (i < n) { r = rel[i]; myrank = atomicAdd(&lcnt[r], 1); }
  __syncthreads();
  if (tid < N_RELC) lbase[tid] = atomicAdd(&cnt[tid], lcnt[tid]);
  __syncthreads();
  if (i < n) pos[i] = lbase[r] + myrank;
}

// Padded segment bases + tile table (1 block, 64 threads).
__global__ void prefix_tiles64(const int* __restrict__ cnt, int* pbase,
                               int* tinfo, int maxt) {
  __shared__ int sb[N_RELC + 1];
  __shared__ int st[N_RELC + 1];
  if (threadIdx.x == 0) {
    int acc = 0, t = 0;
    for (int r = 0; r < N_RELC; ++r) {
      sb[r] = acc; st[r] = t;
      const int nt = (cnt[r] + BM - 1) / BM;
      acc += nt * BM;
      t += nt;
    }
    sb[N_RELC] = acc; st[N_RELC] = t;
  }
  __syncthreads();
  for (int i = threadIdx.x; i <= N_RELC; i += blockDim.x) pbase[i] = sb[i];
  for (int x = threadIdx.x; x < maxt; x += blockDim.x) {
    int v = -1;
    #pragma unroll
    for (int r = 0; r < N_RELC; ++r)
      if (x >= st[r] && x < st[r + 1]) v = (r << 16) | (x - st[r]);
    tinfo[x] = v;
  }
}

__global__ __launch_bounds__(256) void scatter_ptok(
    const int* __restrict__ rel, const int* __restrict__ pos,
    const int* __restrict__ pbase, int* __restrict__ ptok, int n) {
  const int i = blockIdx.x * blockDim.x + threadIdx.x;
  if (i < n) ptok[pbase[rel[i]] + pos[i]] = i;
}

__global__ __launch_bounds__(256) void convert_W(const float* __restrict__ W,
                                                 unsigned short* __restrict__ Ws,
                                                 int welems) {
  const size_t i = ((size_t)blockIdx.x * 256 + threadIdx.x) * 8;
  if (i >= (size_t)welems) return;
  f32x4 a = *reinterpret_cast<const f32x4*>(W + i);
  f32x4 b = *reinterpret_cast<const f32x4*>(W + i + 4);
  bf16x8 o;
  o[0] = f2bf(a[0]); o[1] = f2bf(a[1]); o[2] = f2bf(a[2]); o[3] = f2bf(a[3]);
  o[4] = f2bf(b[0]); o[5] = f2bf(b[1]); o[6] = f2bf(b[2]); o[7] = f2bf(b[3]);
  *reinterpret_cast<bf16x8*>(Ws + i) = o;
}

// ---------------------------------------------------------------------------
// Grouped GEMM, 512 threads (8 waves, 2x4 wave grid; 64x32 output per wave).
// Per thread staging: row = tid>>2 (0..127), kq = tid&3 (8-elem granule).
//   A: 2x f32x4 global (gathered via ptok) -> cvt -> 1x ds_write_b128 (bf16)
//   B: 1x bf16x8 global (pre-converted Ws) -> 1x ds_write_b128
// Pipeline: R holds tile kt+1 while computing tile kt from LDS[kt&1].
// One raw barrier per iter; global loads stay in flight across it.
// ---------------------------------------------------------------------------

#define LOADR(KT)                                                              \
  {                                                                            \
    const int k0_ = (KT) * BK;                                                 \
    ra0 = *reinterpret_cast<const f32x4*>(aptr + k0_);                         \
    ra1 = *reinterpret_cast<const f32x4*>(aptr + k0_ + 4);                     \
    rb  = *reinterpret_cast<const bf16x8*>(bptr + k0_);                        \
  }

#define WRITER(BUF)                                                            \
  {                                                                            \
    bf16x8 aw;                                                                 \
    aw[0] = (short)f2bf(ra0[0]); aw[1] = (short)f2bf(ra0[1]);                  \
    aw[2] = (short)f2bf(ra0[2]); aw[3] = (short)f2bf(ra0[3]);                  \
    aw[4] = (short)f2bf(ra1[0]); aw[5] = (short)f2bf(ra1[1]);                  \
    aw[6] = (short)f2bf(ra1[2]); aw[7] = (short)f2bf(ra1[3]);                  \
    *reinterpret_cast<bf16x8*>(&As[BUF][ldsoff]) = aw;                         \
    *reinterpret_cast<bf16x8*>(&Bs[BUF][ldsoff]) = rb;                         \
  }

#define COMPUTE(BUF)                                                           \
  {                                                                            \
    bf16x8 af[4], bfr[2];                                                      \
    _Pragma("unroll")                                                          \
    for (int m = 0; m < 4; ++m)                                                \
      af[m] = *reinterpret_cast<const bf16x8*>(                                \
          &As[BUF][(wr * 64 + m * 16 + lrow) * LDP + gl * 8]);                 \
    _Pragma("unroll")                                                          \
    for (int nn = 0; nn < 2; ++nn)                                             \
      bfr[nn] = *reinterpret_cast<const bf16x8*>(                              \
          &Bs[BUF][(wc * 32 + nn * 16 + lrow) * LDP + gl * 8]);                \
    _Pragma("unroll")                                                          \
    for (int m = 0; m < 4; ++m)                                                \
      _Pragma("unroll")                                                        \
      for (int nn = 0; nn < 2; ++nn)                                           \
        acc[m][nn] = __builtin_amdgcn_mfma_f32_16x16x32_bf16(                  \
            af[m], bfr[nn], acc[m][nn], 0, 0, 0);                              \
  }

#define PIPE_BARRIER()                                                         \
  asm volatile("s_waitcnt lgkmcnt(0)" ::: "memory");                           \
  __builtin_amdgcn_s_barrier();                                                \
  __builtin_amdgcn_sched_barrier(0);

__global__ __launch_bounds__(512, 4) void grouped_gemm4(
    const float* __restrict__ X, const unsigned short* __restrict__ Ws,
    const int* __restrict__ pbase, const int* __restrict__ tinfo,
    const int* __restrict__ ptok, float* __restrict__ out)
{
  __shared__ unsigned short As[2][BM * LDP];   // 10 KB per buffer
  __shared__ unsigned short Bs[2][BN * LDP];

  const int info = tinfo[blockIdx.x];
  if (info < 0) return;
  const int r = info >> 16;
  const int mt = info & 0xFFFF;
  const int ct = blockIdx.y;
  const int prow0 = pbase[r] + mt * BM;

  const int tid = threadIdx.x;
  const int lane = tid & 63;
  const int wid = tid >> 6;
  const int wr = wid >> 2;          // 0..1 : 64-row band
  const int wc = wid & 3;           // 0..3 : 32-col band
  const int lrow = lane & 15;
  const int gl = lane >> 4;         // k-granule 0..3
  const int lrow4 = gl * 4;

  const int srow = tid >> 2;        // staging row 0..127
  const int kq = tid & 3;           // staging granule
  const int ldsoff = srow * LDP + kq * 8;

  const int tokA = ptok[prow0 + srow];
  const float* aptr = X + (size_t)(tokA < 0 ? 0 : tokA) * EMB + kq * 8;
  const unsigned short* bptr =
      Ws + ((size_t)r * EMB + (size_t)(ct * BN + srow)) * EMB + kq * 8;

  f32x4 acc[4][2];
  const f32x4 vzero = {0.f, 0.f, 0.f, 0.f};
  #pragma unroll
  for (int m = 0; m < 4; ++m)
    #pragma unroll
    for (int nn = 0; nn < 2; ++nn) acc[m][nn] = vzero;

  f32x4 ra0, ra1;
  bf16x8 rb;

  LOADR(0);
  WRITER(0);           // compiler inserts vmcnt wait before cvt
  LOADR(1);
  PIPE_BARRIER();

  for (int kt = 0; kt < NKT - 1; ++kt) {
    const int cur = kt & 1;
    COMPUTE(cur);                      // tile kt; R(kt+1) loads in flight
    WRITER(cur ^ 1);                   // waits R(kt+1), writes other buffer
    if (kt < NKT - 2) LOADR(kt + 2);   // issue next prefetch
    PIPE_BARRIER();                    // lgkm only; vmcnt stays outstanding
  }
  COMPUTE((NKT - 1) & 1);

  // Epilogue: D mapping col=lane&15, row=(lane>>4)*4+reg
  #pragma unroll
  for (int m = 0; m < 4; ++m) {
    const int base = prow0 + wr * 64 + m * 16 + lrow4;
    #pragma unroll
    for (int rg = 0; rg < 4; ++rg) {
      const int tok = ptok[base + rg];
      if (tok >= 0) {
        float* orow = out + (size_t)tok * EMB + ct * BN + wc * 32;
        #pragma unroll
        for (int nn = 0; nn < 2; ++nn)
          orow[nn * 16 + lrow] = acc[m][nn][rg];
      }
    }
  }
}

// Safety-net naive kernel (only if ws too small).
__global__ void naive_kernel(const float* __restrict__ X, const int* __restrict__ rel,
                             const float* __restrict__ W, float* __restrict__ out, int n) {
  int i = blockIdx.x;
  if (i >= n) return;
  int r = rel[i];
  const float* x = X + (size_t)i * EMB;
  const float* Wr = W + (size_t)r * EMB * EMB;
  for (int j = threadIdx.x; j < EMB; j += blockDim.x) {
    const float* w = Wr + (size_t)j * EMB;
    float s = 0.f;
    for (int k = 0; k < EMB; ++k) s += w[k] * x[k];
    out[(size_t)i * EMB + j] = s;
  }
}

extern "C" void kernel_launch(void* const* d_in, const int* in_sizes, int n_in,
                              void* d_out, int out_size, void* d_ws, size_t ws_size,
                              hipStream_t stream) {
  const float* X  = (const float*)d_in[0];
  const int* rel  = (const int*)d_in[1];
  const float* W  = (const float*)d_in[2];
  float* out      = (float*)d_out;
  const int n = in_sizes[1];
  const int welems = in_sizes[2];                 // n_rel * EMB * EMB
  const int padn = n + N_RELC * BM;
  const int maxt = (n + BM - 1) / BM + N_RELC;
  const int maxtp = ((maxt + 7) / 8) * 8;         // multiple of 8 for XCD co-location

  const size_t ints = (size_t)64 + n + padn + maxtp;
  const size_t offW = ((ints * sizeof(int) + 255) / 256) * 256;
  const size_t need = offW + (size_t)welems * 2;

  if (ws_size < need) {
    naive_kernel<<<n, 256, 0, stream>>>(X, rel, W, out, n);
    return;
  }

  int* cnt   = (int*)d_ws;       // 16 (+pad)
  int* pbase = cnt + 16;         // 17
  int* pos   = cnt + 64;         // n
  int* ptok  = pos + n;          // padn
  int* tinfo = ptok + padn;      // maxtp
  unsigned short* Ws = (unsigned short*)((char*)d_ws + offW);

  init_counts<<<1, 32, 0, stream>>>(cnt);
  histo_rank_fill<<<(padn + 255) / 256, 256, 0, stream>>>(rel, cnt, pos, ptok, n, padn);
  prefix_tiles64<<<1, 64, 0, stream>>>(cnt, pbase, tinfo, maxtp);
  scatter_ptok<<<(n + 255) / 256, 256, 0, stream>>>(rel, pos, pbase, ptok, n);
  convert_W<<<(welems / 8 + 255) / 256, 256, 0, stream>>>(W, Ws, welems);

  // grid.x = m-tiles (multiple of 8), grid.y = the 4 column tiles:
  // the 4 ct-blocks of one m-tile share blockIdx.x % 8 -> same XCD L2.
  dim3 grid(maxtp, EMB / BN);
  grouped_gemm4<<<grid, 512, 0, stream>>>(X, Ws, pbase, tinfo, ptok, out);
}